// Round 7
// baseline (833.970 us; speedup 1.0000x reference)
//
#include <hip/hip_runtime.h>

#define NN 100000
#define RR 8
#define BB 8
#define DD 128
#define EE 800000
#define KT 1152                  // 128 (root) + 8*128 (relations)
#define NBLK 782                 // ceil(NN/128)
#define NSEG2 (NBLK * 1024)      // 800768 padded segment keys
#define AMS 136                  // bf16 LDS row stride (272 B, 16B-aligned, ~2-way banks)

typedef __attribute__((ext_vector_type(8))) __bf16 bf16x8;
typedef __attribute__((ext_vector_type(4))) float f32x4;
typedef __attribute__((ext_vector_type(4))) unsigned int u32x4;

__device__ __forceinline__ unsigned short f2bf(float f) {
    unsigned u = __float_as_uint(f);
    u += 0x7fffu + ((u >> 16) & 1u);          // round-to-nearest-even
    return (unsigned short)(u >> 16);
}
__device__ __forceinline__ float bf2f(unsigned short h) {
    return __uint_as_float(((unsigned)h) << 16);
}

// ---------------------------------------------------------------------------
// emb f32 -> bf16, fused with zeroing of cnt (saves the memset dispatch)
// ---------------------------------------------------------------------------
__global__ __launch_bounds__(256) void k_cvt(const float* __restrict__ x,
                                             unsigned short* __restrict__ xh,
                                             int* __restrict__ cnt) {
    int i = blockIdx.x * 256 + threadIdx.x;
    if (i < NSEG2) cnt[i] = 0;
    f32x4 a = ((const f32x4*)x)[2 * i];
    f32x4 b = ((const f32x4*)x)[2 * i + 1];
    u32x4 o;
    o[0] = (unsigned)f2bf(a[0]) | ((unsigned)f2bf(a[1]) << 16);
    o[1] = (unsigned)f2bf(a[2]) | ((unsigned)f2bf(a[3]) << 16);
    o[2] = (unsigned)f2bf(b[0]) | ((unsigned)f2bf(b[1]) << 16);
    o[3] = (unsigned)f2bf(b[2]) | ((unsigned)f2bf(b[3]) << 16);
    ((u32x4*)xh)[i] = o;
}

// ---------------------------------------------------------------------------
// Counting sort by key = (dst>>7)*1024 + rel*128 + (dst&127)
// ---------------------------------------------------------------------------
__global__ __launch_bounds__(256) void k_cnt(const int* __restrict__ ei,
                                             const int* __restrict__ et,
                                             int* __restrict__ cnt) {
    int e = blockIdx.x * 256 + threadIdx.x;
    if (e < EE) {
        int d = ei[EE + e];
        atomicAdd(&cnt[(d >> 7) * 1024 + et[e] * 128 + (d & 127)], 1);
    }
}

__global__ __launch_bounds__(256) void k_scan_local(const int* __restrict__ cnt,
                                                    int* __restrict__ loc,
                                                    int* __restrict__ bsum) {
    __shared__ int tmp[256];
    int t = threadIdx.x, i = blockIdx.x * 256 + t;
    int v = cnt[i];
    tmp[t] = v; __syncthreads();
    int val = v;
#pragma unroll
    for (int d = 1; d < 256; d <<= 1) {
        int a = (t >= d) ? tmp[t - d] : 0;
        __syncthreads();
        val += a; tmp[t] = val;
        __syncthreads();
    }
    loc[i] = val - v;
    if (t == 255) bsum[blockIdx.x] = val;
}

__global__ void k_scan_bsum(const int* __restrict__ bsum, int* __restrict__ boff) {
    __shared__ int tmp[256];
    const int NB = NSEG2 / 256;             // 3128
    const int CH = 13;                      // 256*13 >= 3128
    int t = threadIdx.x;
    int base = t * CH, s = 0;
    for (int j = 0; j < CH; ++j) { int idx = base + j; if (idx < NB) s += bsum[idx]; }
    tmp[t] = s; __syncthreads();
    int val = s;
#pragma unroll
    for (int d = 1; d < 256; d <<= 1) {
        int a = (t >= d) ? tmp[t - d] : 0;
        __syncthreads();
        val += a; tmp[t] = val;
        __syncthreads();
    }
    int run = val - s;
    for (int j = 0; j < CH; ++j) { int idx = base + j; if (idx < NB) { boff[idx] = run; run += bsum[idx]; } }
}

// global scan completion + per-(block,rel) range starts (fused)
__global__ __launch_bounds__(256) void k_scan_addroff(int* __restrict__ loc,
                                                      const int* __restrict__ boff,
                                                      int* __restrict__ roff) {
    int i = blockIdx.x * 256 + threadIdx.x;
    int v = loc[i] + boff[i >> 8];
    loc[i] = v;
    if ((i & 127) == 0) roff[(i >> 10) * 8 + ((i >> 7) & 7)] = v;
    if (i == 0) roff[NBLK * 8] = EE;
}

// scatter: src index; segoff is the cursor (post-scatter segoff = segment END;
// k_gemm recovers beg = segoff[key] - cnt[key])
__global__ __launch_bounds__(256) void k_scatter(const int* __restrict__ ei,
                                                 const int* __restrict__ et,
                                                 int* __restrict__ segoff,
                                                 int* __restrict__ spk) {
    int e = blockIdx.x * 256 + threadIdx.x;
    if (e < EE) {
        int d = ei[EE + e];
        int key = (d >> 7) * 1024 + et[e] * 128 + (d & 127);
        int pos = atomicAdd(&segoff[key], 1);
        spk[pos] = ei[e];
    }
}

// ---------------------------------------------------------------------------
// B prep (both layers, blockIdx.y selects layer): BT[o][k] bf16 hi/lo
// ---------------------------------------------------------------------------
__global__ __launch_bounds__(256) void k_prepB(const float* __restrict__ root1,
                                               const float* __restrict__ comp1,
                                               const float* __restrict__ basis1,
                                               const float* __restrict__ root2,
                                               const float* __restrict__ comp2,
                                               const float* __restrict__ basis2,
                                               unsigned short* __restrict__ Bhi1,
                                               unsigned short* __restrict__ Blo1,
                                               unsigned short* __restrict__ Bhi2,
                                               unsigned short* __restrict__ Blo2) {
    const int layer = blockIdx.y;
    const float* root  = layer ? root2  : root1;
    const float* comp  = layer ? comp2  : comp1;
    const float* basis = layer ? basis2 : basis1;
    unsigned short* Bhi = layer ? Bhi2 : Bhi1;
    unsigned short* Blo = layer ? Blo2 : Blo1;
    int idx = blockIdx.x * 256 + threadIdx.x;   // DD*KT = 147456
    if (idx >= DD * KT) return;
    int o = idx / KT, k = idx - o * KT;
    float v;
    if (k < DD) {
        v = root[k * DD + o];
    } else {
        int r = (k - DD) >> 7, i = (k - DD) & 127;
        float s = 0.f;
#pragma unroll
        for (int b = 0; b < BB; ++b)
            s += comp[r * BB + b] * basis[((size_t)b * DD + i) * DD + o];
        v = s;
    }
    unsigned short hi = f2bf(v);
    Bhi[idx] = hi;
    Blo[idx] = f2bf(v - bf2f(hi));
}

// ---------------------------------------------------------------------------
// Fused agg + GEMM, per-relation full-row scheme (round 6 structure, staging
// width bugs fixed: root copy is 64 bf16/thread, mean pack is 32 bf16/half).
// ---------------------------------------------------------------------------
template <bool WRITE_H1>
__global__ __launch_bounds__(256, 2) void k_gemm(
    const unsigned short* __restrict__ xh,
    const unsigned short* __restrict__ Bhi,
    const unsigned short* __restrict__ Blo,
    const float* __restrict__ bias,
    const int* __restrict__ spk,
    const int* __restrict__ roff,
    const int* __restrict__ segend,     // post-scatter segoff = segment ends
    const int* __restrict__ cnt,
    unsigned short* __restrict__ h1h,
    float* __restrict__ outf)
{
    __shared__ unsigned short Am[128 * AMS];   // 34.8 KB  mean/root tile (K=128 slab)
    __shared__ unsigned short Ae[64 * AMS];    // 17.4 KB  edge-row staging chunk
    __shared__ int reb[9];

    const int tid = threadIdx.x;
    const int b = blockIdx.x;
    const int M0 = b * 128;

    if (tid < 9) reb[tid] = roff[b * 8 + tid];

    const int wave = tid >> 6, lane = tid & 63;
    const int quad = lane >> 4, lm = lane & 15;
    const int node = tid >> 1, hh = tid & 1;     // owner: 2 threads/node, 64 cols each
    const int erow = tid >> 2, eq = tid & 3;     // staging: 4 threads/edge, 32 cols each

    float bv[8];
#pragma unroll
    for (int nt = 0; nt < 8; ++nt) bv[nt] = bias[nt * 16 + lm];

    f32x4 acc[2][8];
#pragma unroll
    for (int a = 0; a < 2; ++a)
#pragma unroll
        for (int n = 0; n < 8; ++n) acc[a][n] = (f32x4){0.f, 0.f, 0.f, 0.f};

    // MFMA over the current Am slab against global-B cols kg..kg+127
    auto mfma_phase = [&](int kg) {
#pragma unroll
        for (int kk = 0; kk < 4; ++kk) {
            bf16x8 af0 = __builtin_bit_cast(bf16x8,
                *(const u32x4*)&Am[(wave * 32 + lm) * AMS + kk * 32 + quad * 8]);
            bf16x8 af1 = __builtin_bit_cast(bf16x8,
                *(const u32x4*)&Am[(wave * 32 + 16 + lm) * AMS + kk * 32 + quad * 8]);
            const int kb = kg + kk * 32 + quad * 8;
#pragma unroll
            for (int nt = 0; nt < 8; ++nt) {
                const size_t ro = (size_t)(nt * 16 + lm) * KT + kb;
                bf16x8 bh = __builtin_bit_cast(bf16x8, *(const u32x4*)(Bhi + ro));
                bf16x8 bl = __builtin_bit_cast(bf16x8, *(const u32x4*)(Blo + ro));
                acc[0][nt] = __builtin_amdgcn_mfma_f32_16x16x32_bf16(af0, bh, acc[0][nt], 0, 0, 0);
                acc[0][nt] = __builtin_amdgcn_mfma_f32_16x16x32_bf16(af0, bl, acc[0][nt], 0, 0, 0);
                acc[1][nt] = __builtin_amdgcn_mfma_f32_16x16x32_bf16(af1, bh, acc[1][nt], 0, 0, 0);
                acc[1][nt] = __builtin_amdgcn_mfma_f32_16x16x32_bf16(af1, bl, acc[1][nt], 0, 0, 0);
            }
        }
    };

    // ---------- root phase: Am = this block's own xh rows ----------
    {
        int nidx = M0 + node; if (nidx > NN - 1) nidx = NN - 1;
        const u32x4* px = (const u32x4*)(xh + (size_t)nidx * DD + hh * 64);
        u32x4 a0 = px[0], a1 = px[1], a2 = px[2], a3 = px[3];
        u32x4 a4 = px[4], a5 = px[5], a6 = px[6], a7 = px[7];   // FIX: full 64 bf16
        u32x4* pa = (u32x4*)&Am[node * AMS + hh * 64];
        pa[0] = a0; pa[1] = a1; pa[2] = a2; pa[3] = a3;
        pa[4] = a4; pa[5] = a5; pa[6] = a6; pa[7] = a7;
    }
    __syncthreads();
    mfma_phase(0);

    // ---------- relation phases ----------
    for (int r = 0; r < RR; ++r) {
        const int rb = reb[r], rend = reb[r + 1];
        const int g = b * 1024 + r * 128 + node;
        const int send = segend[g];
        const int cs = cnt[g];
        const int beg = send - cs;
        const int nch = (rend - rb + 63) >> 6;

        float v[64];
#pragma unroll
        for (int j = 0; j < 64; ++j) v[j] = 0.f;

        // prefetch chunk 0
        u32x4 p0 = {}, p1 = {}, p2 = {}, p3 = {};
        {
            int e = rb + erow;
            if (e < rend) {
                int s = spk[e];
                const u32x4* px = (const u32x4*)(xh + (size_t)s * DD + eq * 32);
                p0 = px[0]; p1 = px[1]; p2 = px[2]; p3 = px[3];
            }
        }

        for (int c = 0; c < nch; ++c) {
            const int cb0 = rb + c * 64;
            __syncthreads();                       // Ae consumers / prev MFMA done
            if (cb0 + erow < rend) {
                u32x4* pa = (u32x4*)&Ae[erow * AMS + eq * 32];
                pa[0] = p0; pa[1] = p1; pa[2] = p2; pa[3] = p3;
            }
            {   // prefetch chunk c+1 (overlaps the reduce below)
                int e = cb0 + 64 + erow;
                if (e < rend) {
                    int s = spk[e];
                    const u32x4* px = (const u32x4*)(xh + (size_t)s * DD + eq * 32);
                    p0 = px[0]; p1 = px[1]; p2 = px[2]; p3 = px[3];
                }
            }
            __syncthreads();                       // Ae ready
            int lo = beg > cb0 ? beg : cb0;
            int hi2 = send < cb0 + 64 ? send : cb0 + 64;
            for (int e2 = lo; e2 < hi2; ++e2) {
                const int slot = e2 - cb0;
                const u32x4* pe0 = (const u32x4*)&Ae[slot * AMS + hh * 32];
                const u32x4* pe1 = (const u32x4*)&Ae[slot * AMS + 64 + hh * 32];
                u32x4 qa0 = pe0[0], qa1 = pe0[1], qa2 = pe0[2], qa3 = pe0[3];
                u32x4 qb0 = pe1[0], qb1 = pe1[1], qb2 = pe1[2], qb3 = pe1[3];
#pragma unroll
                for (int j = 0; j < 4; ++j) {
                    unsigned u;
                    u = qa0[j]; v[2*j]      += __uint_as_float(u << 16); v[2*j+1]    += __uint_as_float(u & 0xFFFF0000u);
                    u = qa1[j]; v[8+2*j]    += __uint_as_float(u << 16); v[8+2*j+1]  += __uint_as_float(u & 0xFFFF0000u);
                    u = qa2[j]; v[16+2*j]   += __uint_as_float(u << 16); v[16+2*j+1] += __uint_as_float(u & 0xFFFF0000u);
                    u = qa3[j]; v[24+2*j]   += __uint_as_float(u << 16); v[24+2*j+1] += __uint_as_float(u & 0xFFFF0000u);
                    u = qb0[j]; v[32+2*j]   += __uint_as_float(u << 16); v[32+2*j+1] += __uint_as_float(u & 0xFFFF0000u);
                    u = qb1[j]; v[40+2*j]   += __uint_as_float(u << 16); v[40+2*j+1] += __uint_as_float(u & 0xFFFF0000u);
                    u = qb2[j]; v[48+2*j]   += __uint_as_float(u << 16); v[48+2*j+1] += __uint_as_float(u & 0xFFFF0000u);
                    u = qb3[j]; v[56+2*j]   += __uint_as_float(u << 16); v[56+2*j+1] += __uint_as_float(u & 0xFFFF0000u);
                }
            }
        }
        if (nch == 0) __syncthreads();             // prev-MFMA drain before Am write

        // ---- pack mean into Am (FIX: full 32 bf16 per half-slab)
        const float inv = 1.0f / (float)(cs > 1 ? cs : 1);
        {
            unsigned pk[16];
#pragma unroll
            for (int j = 0; j < 16; ++j)
                pk[j] = (unsigned)f2bf(v[2*j] * inv) | ((unsigned)f2bf(v[2*j+1] * inv) << 16);
            u32x4* pa = (u32x4*)&Am[node * AMS + hh * 32];
            pa[0] = (u32x4){pk[0],  pk[1],  pk[2],  pk[3]};
            pa[1] = (u32x4){pk[4],  pk[5],  pk[6],  pk[7]};
            pa[2] = (u32x4){pk[8],  pk[9],  pk[10], pk[11]};
            pa[3] = (u32x4){pk[12], pk[13], pk[14], pk[15]};
#pragma unroll
            for (int j = 0; j < 16; ++j)
                pk[j] = (unsigned)f2bf(v[32+2*j] * inv) | ((unsigned)f2bf(v[32+2*j+1] * inv) << 16);
            u32x4* pb = (u32x4*)&Am[node * AMS + 64 + hh * 32];
            pb[0] = (u32x4){pk[0],  pk[1],  pk[2],  pk[3]};
            pb[1] = (u32x4){pk[4],  pk[5],  pk[6],  pk[7]};
            pb[2] = (u32x4){pk[8],  pk[9],  pk[10], pk[11]};
            pb[3] = (u32x4){pk[12], pk[13], pk[14], pk[15]};
        }
        __syncthreads();                           // Am ready
        mfma_phase(DD + r * DD);
    }

    // ---------- epilogue (C/D: col=lane&15, row=quad*4+reg) ----------
#pragma unroll
    for (int mt = 0; mt < 2; ++mt) {
#pragma unroll
        for (int nt = 0; nt < 8; ++nt) {
#pragma unroll
            for (int rg = 0; rg < 4; ++rg) {
                int row = M0 + wave * 32 + mt * 16 + quad * 4 + rg;
                if (row < NN) {
                    int col = nt * 16 + lm;
                    float vv = acc[mt][nt][rg] + bv[nt];
                    if (WRITE_H1) h1h[(size_t)row * DD + col] = f2bf(fmaxf(vv, 0.f));
                    else          outf[(size_t)row * DD + col] = vv;
                }
            }
        }
    }
}

// ---------------------------------------------------------------------------

extern "C" void kernel_launch(void* const* d_in, const int* in_sizes, int n_in,
                              void* d_out, int out_size, void* d_ws, size_t ws_size,
                              hipStream_t stream) {
    const int*   ei     = (const int*)d_in[0];
    const int*   et     = (const int*)d_in[1];
    const float* emb    = (const float*)d_in[2];
    const float* basis1 = (const float*)d_in[3];
    const float* comp1  = (const float*)d_in[4];
    const float* root1  = (const float*)d_in[5];
    const float* bias1  = (const float*)d_in[6];
    const float* basis2 = (const float*)d_in[7];
    const float* comp2  = (const float*)d_in[8];
    const float* root2  = (const float*)d_in[9];
    const float* bias2  = (const float*)d_in[10];
    float* out = (float*)d_out;
    (void)in_sizes; (void)n_in; (void)out_size; (void)ws_size;

    char* ws = (char*)d_ws;
    int*            cnt    = (int*)(ws + 0);           // 3,203,072 B
    int*            segoff = (int*)(ws + 3203072);     // 3,203,072 B (post-scatter = ends)
    int*            spk    = (int*)(ws + 6406144);     // 3,200,000 B
    int*            bsum   = (int*)(ws + 9606144);     // 12,512 B
    int*            boff   = (int*)(ws + 9618656);     // 12,512 B
    int*            roffp  = (int*)(ws + 9631168);     // 25,028 B (pad to 9,656,320)
    unsigned short* Bhi1   = (unsigned short*)(ws + 9656320);    // 294,912 B each
    unsigned short* Blo1   = (unsigned short*)(ws + 9951232);
    unsigned short* Bhi2   = (unsigned short*)(ws + 10246144);
    unsigned short* Blo2   = (unsigned short*)(ws + 10541056);
    unsigned short* embh   = (unsigned short*)(ws + 10835968);   // 25.6 MB
    unsigned short* h1h    = (unsigned short*)(ws + 36435968);   // 25.6 MB -> end 62.0 MB

    k_cvt         <<<NN * DD / (256 * 8), 256, 0, stream>>>(emb, embh, cnt);
    k_cnt         <<<(EE + 255) / 256, 256, 0, stream>>>(ei, et, cnt);
    k_scan_local  <<<NSEG2 / 256, 256, 0, stream>>>(cnt, segoff, bsum);
    k_scan_bsum   <<<1, 256, 0, stream>>>(bsum, boff);
    k_scan_addroff<<<NSEG2 / 256, 256, 0, stream>>>(segoff, boff, roffp);
    k_scatter     <<<(EE + 255) / 256, 256, 0, stream>>>(ei, et, segoff, spk);

    dim3 pgrid((DD * KT + 255) / 256, 2);
    k_prepB<<<pgrid, 256, 0, stream>>>(root1, comp1, basis1, root2, comp2, basis2,
                                       Bhi1, Blo1, Bhi2, Blo2);

    k_gemm<true> <<<NBLK, 256, 0, stream>>>(embh, Bhi1, Blo1, bias1, spk, roffp, segoff, cnt, h1h, nullptr);
    k_gemm<false><<<NBLK, 256, 0, stream>>>(h1h,  Bhi2, Blo2, bias2, spk, roffp, segoff, cnt, nullptr, out);
}